// Round 1
// baseline (109.081 us; speedup 1.0000x reference)
//
#include <hip/hip_runtime.h>

#define HH 2048
#define WW 2048
#define NB 1024
#define TW 64   // tile width in pixels
#define TH 16   // tile height in pixels
// block = 256 threads; each thread owns 4 consecutive x-pixels (float4 stores)

__global__ __launch_bounds__(256, 4) void paint_kernel(const float4* __restrict__ boxes,
                                                       float* __restrict__ out) {
    __shared__ short sy1[NB], sx1[NB], sy2[NB], sx2[NB];
    __shared__ short slist[NB];
    __shared__ unsigned long long imask[4];
    __shared__ unsigned long long fmask[4];

    const int tid  = threadIdx.x;
    const int lane = tid & 63;
    const int wid  = tid >> 6;
    const int tileX = blockIdx.x * TW;
    const int tileY = blockIdx.y * TH;

    // ---- load boxes, convert to pixel coords (truncate like .astype(int32)) ----
    for (int i = tid; i < NB; i += 256) {
        float4 b = boxes[i];
        int y1 = (int)(b.x * (float)HH); y1 = max(y1, 0);
        int x1 = (int)(b.y * (float)WW); x1 = max(x1, 0);
        int y2 = (int)(b.z * (float)HH); y2 = min(y2, HH);
        int x2 = (int)(b.w * (float)WW); x2 = min(x2, WW);
        sy1[i] = (short)y1; sx1[i] = (short)x1;
        sy2[i] = (short)y2; sx2[i] = (short)x2;
    }
    __syncthreads();

    // ---- ordered compaction of boxes intersecting this tile ----
    int cnt = 0;        // uniform across block
    int lastFull = -1;  // uniform: last box fully covering the tile
    for (int c = 0; c < NB / 256; ++c) {
        int b = c * 256 + tid;
        int y1 = sy1[b], x1 = sx1[b], y2 = sy2[b], x2 = sx2[b];
        bool inter = (y1 < tileY + TH) && (y2 > tileY) &&
                     (x1 < tileX + TW) && (x2 > tileX) &&
                     (y1 < y2) && (x1 < x2);
        bool full  = (y1 <= tileY) && (y2 >= tileY + TH) &&
                     (x1 <= tileX) && (x2 >= tileX + TW);
        unsigned long long mi = __ballot(inter);
        unsigned long long mf = __ballot(full);
        if (lane == 0) { imask[wid] = mi; fmask[wid] = mf; }
        __syncthreads();
        int base = cnt;
        for (int w = 0; w < wid; ++w) base += __popcll(imask[w]);
        if (inter) {
            int off = base + __popcll(mi & ((1ull << lane) - 1ull));
            slist[off] = (short)b;
        }
        int total = 0;
        for (int w = 0; w < 4; ++w) total += __popcll(imask[w]);
        cnt += total;
        for (int w = 3; w >= 0; --w) {
            unsigned long long m = fmask[w];
            if (m) { lastFull = c * 256 + w * 64 + 63 - __clzll(m); break; }
        }
        __syncthreads();  // protect imask/fmask reuse next chunk
    }

    // ---- per-pixel backward ownership scan over the culled list ----
    const int px0 = tileX + (tid & 15) * 4;
    const int py  = tileY + (tid >> 4);

    float vals[5][4];
    for (int k = 0; k < 4; ++k) {
        int px = px0 + k;
        int found = lastFull;  // default: tile-covering box (or -1 => zeros)
        for (int j = cnt - 1; j >= 0; --j) {
            int bi = slist[j];
            if (bi <= lastFull) break;  // list ascending: rest is pruned
            if (py >= sy1[bi] && py < sy2[bi] && px >= sx1[bi] && px < sx2[bi]) {
                found = bi;
                break;
            }
        }
        if (found >= 0) {
            float4 bv = boxes[found];   // 16 KB total, L1/L2-hot
            vals[0][k] = 1.0f;
            vals[1][k] = bv.x; vals[2][k] = bv.y;
            vals[3][k] = bv.z; vals[4][k] = bv.w;
        } else {
            vals[0][k] = 0.0f; vals[1][k] = 0.0f; vals[2][k] = 0.0f;
            vals[3][k] = 0.0f; vals[4][k] = 0.0f;
        }
    }

    const size_t pbase = (size_t)py * WW + px0;
    #pragma unroll
    for (int c = 0; c < 5; ++c) {
        float4 v = make_float4(vals[c][0], vals[c][1], vals[c][2], vals[c][3]);
        *(float4*)(out + (size_t)c * (HH * WW) + pbase) = v;
    }
}

extern "C" void kernel_launch(void* const* d_in, const int* in_sizes, int n_in,
                              void* d_out, int out_size, void* d_ws, size_t ws_size,
                              hipStream_t stream) {
    const float4* boxes = (const float4*)d_in[0];
    float* out = (float*)d_out;
    dim3 grid(WW / TW, HH / TH);  // 32 x 128 = 4096 blocks
    dim3 block(256);
    paint_kernel<<<grid, block, 0, stream>>>(boxes, out);
}

// Round 2
// 91.822 us; speedup vs baseline: 1.1880x; 1.1880x over previous
//
#include <hip/hip_runtime.h>

#define HH 2048
#define WW 2048
#define NB 1024
#define TW 128  // tile width
#define TH 32   // tile height
// 256 threads/block; thread owns a 4x4 pixel patch: qx = tid&31 (x-quad),
// ry = tid>>5 (row group), rows py0..py0+3. Wave stores = 32 lanes x 16 B
// = 512 B contiguous per row segment -> fully coalesced.

__global__ __launch_bounds__(256, 4) void paint_kernel(const float4* __restrict__ boxes,
                                                       float* __restrict__ out) {
    __shared__ unsigned long long imaskS[4][4];  // [chunk][wave]
    __shared__ unsigned long long fmaskS[4][4];
    __shared__ uint2 clist[NB];  // packed coords of pruned candidates (idx > lastFull)
    __shared__ short cidxS[NB];

    const int tid  = threadIdx.x;
    const int lane = tid & 63;
    const int wid  = tid >> 6;
    const int tileX = blockIdx.x * TW;
    const int tileY = blockIdx.y * TH;

    // ---- pass 1: load + convert + ballot; coords stay in registers ----
    int ry1[4], rx1[4], ry2[4], rx2[4];
    bool rint[4];
    #pragma unroll
    for (int c = 0; c < 4; ++c) {
        float4 bx = boxes[c * 256 + tid];
        int y1 = max(0, (int)(bx.x * (float)HH));   // trunc-toward-zero == astype(int32)
        int x1 = max(0, (int)(bx.y * (float)WW));
        int y2 = min(HH, (int)(bx.z * (float)HH));
        int x2 = min(WW, (int)(bx.w * (float)WW));
        ry1[c] = y1; rx1[c] = x1; ry2[c] = y2; rx2[c] = x2;
        bool valid = (y1 < y2) && (x1 < x2);
        bool inter = valid && (y1 < tileY + TH) && (y2 > tileY) &&
                     (x1 < tileX + TW) && (x2 > tileX);
        bool full  = (y1 <= tileY) && (y2 >= tileY + TH) &&
                     (x1 <= tileX) && (x2 >= tileX + TW);
        rint[c] = inter;
        unsigned long long mi = __ballot(inter);
        unsigned long long mf = __ballot(full);
        if (lane == 0) { imaskS[c][wid] = mi; fmaskS[c][wid] = mf; }
    }
    __syncthreads();  // barrier 1

    // ---- lastFull: highest-index box fully covering the tile (block-uniform) ----
    int lastFull = -1;
    #pragma unroll
    for (int c = 3; c >= 0; --c)
        #pragma unroll
        for (int w = 3; w >= 0; --w)
            if (lastFull < 0) {
                unsigned long long m = fmaskS[c][w];
                if (m) lastFull = c * 256 + w * 64 + 63 - __clzll(m);
            }

    // ---- prune masks to idx > lastFull; compute compaction offsets ----
    int cnt_all = 0;
    int myoff[4];
    #pragma unroll
    for (int c = 0; c < 4; ++c) {
        #pragma unroll
        for (int w = 0; w < 4; ++w) {
            unsigned long long m = imaskS[c][w];
            int d = lastFull - (c * 256 + w * 64);
            if (d >= 63) m = 0;
            else if (d >= 0) m &= (~0ull) << (d + 1);
            if (w == wid)
                myoff[c] = cnt_all + __popcll(m & ((1ull << lane) - 1ull));
            cnt_all += __popcll(m);
        }
    }

    // ---- sparse compaction writes (coords still in registers) ----
    #pragma unroll
    for (int c = 0; c < 4; ++c) {
        int b = c * 256 + tid;
        if (rint[c] && b > lastFull) {
            clist[myoff[c]] = make_uint2(((unsigned)ry1[c] << 16) | (unsigned)rx1[c],
                                         ((unsigned)ry2[c] << 16) | (unsigned)rx2[c]);
            cidxS[myoff[c]] = (short)b;
        }
    }
    __syncthreads();  // barrier 2

    const int qx  = tid & 31;
    const int px0 = tileX + qx * 4;
    const int ry  = tid >> 5;
    const int py0 = tileY + ry * 4;

    if (cnt_all == 0) {
        // ---- uniform fast path: whole tile = lastFull box (or zeros) ----
        float4 bv = make_float4(0.f, 0.f, 0.f, 0.f);
        float on = 0.f;
        if (lastFull >= 0) { bv = boxes[lastFull]; on = 1.f; }
        float vals[5] = {on, bv.x, bv.y, bv.z, bv.w};
        #pragma unroll
        for (int ch = 0; ch < 5; ++ch) {
            float4 v = make_float4(vals[ch], vals[ch], vals[ch], vals[ch]);
            size_t base = (size_t)ch * (HH * WW);
            #pragma unroll
            for (int s = 0; s < 4; ++s)
                *(float4*)(out + base + (size_t)(py0 + s) * WW + px0) = v;
        }
    } else {
        // ---- per-pixel ownership: ascending overwrite over tiny pruned list ----
        int fnd[4][4];
        #pragma unroll
        for (int s = 0; s < 4; ++s)
            #pragma unroll
            for (int k = 0; k < 4; ++k) fnd[s][k] = lastFull;
        for (int j = 0; j < cnt_all; ++j) {
            uint2 pc = clist[j];           // one ds_read_b64
            int bidx = cidxS[j];
            int by1 = (int)(pc.x >> 16), bx1 = (int)(pc.x & 0xffff);
            int by2 = (int)(pc.y >> 16), bx2 = (int)(pc.y & 0xffff);
            #pragma unroll
            for (int s = 0; s < 4; ++s) {
                int py = py0 + s;
                bool yin = (py >= by1) && (py < by2);
                #pragma unroll
                for (int k = 0; k < 4; ++k) {
                    int px = px0 + k;
                    if (yin && px >= bx1 && px < bx2) fnd[s][k] = bidx;
                }
            }
        }
        #pragma unroll
        for (int s = 0; s < 4; ++s) {
            float4 v[5];
            #pragma unroll
            for (int k = 0; k < 4; ++k) {
                int f = fnd[s][k];
                float4 bv = (f >= 0) ? boxes[f] : make_float4(0.f, 0.f, 0.f, 0.f);
                float on = (f >= 0) ? 1.f : 0.f;
                ((float*)&v[0])[k] = on;
                ((float*)&v[1])[k] = bv.x;
                ((float*)&v[2])[k] = bv.y;
                ((float*)&v[3])[k] = bv.z;
                ((float*)&v[4])[k] = bv.w;
            }
            size_t pb = (size_t)(py0 + s) * WW + px0;
            #pragma unroll
            for (int ch = 0; ch < 5; ++ch)
                *(float4*)(out + (size_t)ch * (HH * WW) + pb) = v[ch];
        }
    }
}

extern "C" void kernel_launch(void* const* d_in, const int* in_sizes, int n_in,
                              void* d_out, int out_size, void* d_ws, size_t ws_size,
                              hipStream_t stream) {
    const float4* boxes = (const float4*)d_in[0];
    float* out = (float*)d_out;
    dim3 grid(WW / TW, HH / TH);  // 16 x 64 = 1024 blocks
    dim3 block(256);
    paint_kernel<<<grid, block, 0, stream>>>(boxes, out);
}